// Round 5
// baseline (9619.040 us; speedup 1.0000x reference)
//
#include <hip/hip_runtime.h>
#include <hip/hip_bf16.h>

// ---------------------------------------------------------------------------
// 2-layer tanh RNN (B=128, T=512, H=1024) + LN + vocab projection.
// Persistent fused pipeline, weight-stationary f16 fragments in VGPRs,
// per-group (16 batch rows) spin barriers.
//
//   L0 : h0[t]   = tanh(etab[x[:,t]] + Wh0·h0[t-1])        t in [0,512)
//   XP : xp[t-1] = wi1·h0[t-1] + bi1                        t in [1,512]
//   L1 : h1[t-2] = tanh(xp[t-2] + Wh1·h1[t-3])             t in [2,513]
//   PR : out[t-3] = algebraic-LN(h1[t-3]) @ (g*pw)^T + c    t in [3,514]
//
// R10->R11: HANG-PROOF STORE-BASED XCD-LOCAL BARRIER. R10's failure was
// container-level ("failed twice"), likely infra; but to make the resubmit
// safe under EITHER explanation the FAST barrier is now timeout-guarded
// with a compose-safe fallback:
//   arrival : sc0-store step t+1 into own slot cnt[g*32+rid]  (XCD L2)
//   fast    : wave 0 lanes 0..25 sc0-poll all 26 slots, <=128 polls (~16us)
//   publish : UNCONDITIONALLY one agent-scope counter atomic per block/step
//             (after fast exit, or at timeout BEFORE the fallback spin)
//   fallback: timed-out block spins on the agent counter (R6-proven) until
//             26*(t+1).  Every block publishes both signals every step, so
//             any mix of fast/timeout observers composes; data lives in the
//             shared XCD L2 (drained via in-asm vmcnt(0) before arrival),
//             so either flag path orders correctly. A broken fast-barrier
//             premise now yields a PASSING ~10ms run, never a hang.
// Healthy-case insurance cost: one fire-and-forget IF atomic per block/step
// (ack can only stall wave 0's next stage vmcnt(0), ~0.1us/step).
//
// R8-proven and unchanged: XCD-local sc0 DATA path (A-tile stage, xp loads,
// h/xp stores -> FETCH 329->67 MB, WRITE 603->81 MB), XCC_ID-uniformity
// detection (FAST only if all 26 blocks of the group share one XCD),
// agent-scope SLOW path for non-uniform groups.
//
// LDS note: As row stride 516 dwords gives the uniform-minimum 8 dwords/bank
// for all wave64 b128 patterns; SQ_LDS_BANK_CONFLICT ~1.09e8 is intrinsic.
//
// INPUT DTYPE DETECTED AT RUNTIME (bf16 vs fp32), flag steers all I/O.
// ws need: 3.01 MB.
// ---------------------------------------------------------------------------

typedef __bf16 bf16;
typedef _Float16 f16;
typedef _Float16 f16x8 __attribute__((ext_vector_type(8)));
typedef float f32x4 __attribute__((ext_vector_type(4)));
typedef unsigned long long u64;

#define TSTEPS 512
#define BATCH  128
#define HID    1024
#define NST    515
#define FAST_SPIN_MAX 128

__device__ __forceinline__ f32x4 mfma16(f16x8 a, f16x8 b, f32x4 c) {
    return __builtin_amdgcn_mfma_f32_16x16x32_f16(a, b, c, 0, 0, 0);
}

// ---- agent-coherent (sc0|sc1, L1/L2-bypassing) helpers (SLOW path) ----
__device__ __forceinline__ f16x8 lda16(const f16* p) {   // 16B via 2x8B
    union { u64 u[2]; f16x8 v; } c;
    c.u[0] = __hip_atomic_load((const u64*)p,     __ATOMIC_RELAXED, __HIP_MEMORY_SCOPE_AGENT);
    c.u[1] = __hip_atomic_load((const u64*)p + 1, __ATOMIC_RELAXED, __HIP_MEMORY_SCOPE_AGENT);
    return c.v;
}
__device__ __forceinline__ void sth2(f16* p, f16 v) {    // 2B coherent store
    union { f16 f; unsigned short s; } c; c.f = v;
    __hip_atomic_store((unsigned short*)p, c.s, __ATOMIC_RELAXED, __HIP_MEMORY_SCOPE_AGENT);
}
__device__ __forceinline__ void stf4(float* p, float v) { // 4B coherent store
    union { float f; unsigned u; } c; c.f = v;
    __hip_atomic_store((unsigned*)p, c.u, __ATOMIC_RELAXED, __HIP_MEMORY_SCOPE_AGENT);
}
__device__ __forceinline__ float ldf4c(const float* p) {  // 4B coherent load
    union { float f; unsigned u; } c;
    c.u = __hip_atomic_load((const unsigned*)p, __ATOMIC_RELAXED, __HIP_MEMORY_SCOPE_AGENT);
    return c.f;
}

__device__ __forceinline__ unsigned f16bits32(f16 v) {
    union { f16 f; unsigned short s; } c; c.f = v; return (unsigned)c.s;
}

// dual-dtype scalar load (read-only inputs, plain cached)
__device__ __forceinline__ float ldf(const void* p, size_t i, bool f32) {
    return f32 ? ((const float*)p)[i] : (float)((const bf16*)p)[i];
}

// --------------------------- dtype detector --------------------------------
__global__ void det_kernel(const unsigned short* __restrict__ e, unsigned* __restrict__ flag) {
    int tid = threadIdx.x;                       // 1 block x 256
    int cnt = 0;
    for (int i = tid; i < 1024; i += 256) {
        unsigned short u = e[i];
        int ex = (u >> 7) & 0xFF;
        if ((ex >= 110 && ex <= 131) || u == 0) cnt++;
    }
    __shared__ int sh[256];
    sh[tid] = cnt; __syncthreads();
    for (int s = 128; s > 0; s >>= 1) { if (tid < s) sh[tid] += sh[tid + s]; __syncthreads(); }
    if (tid == 0) *flag = (sh[0] >= 768) ? 0u : 1u;
}

// --------------------------- setup kernels ---------------------------------
__global__ void etab_kernel(const void* __restrict__ emb, const void* __restrict__ wi0,
                            const void* __restrict__ bi0, const unsigned* __restrict__ flag,
                            float* __restrict__ etab) {
    const bool f32 = (*flag != 0);
    int i = blockIdx.x * 256 + threadIdx.x;      // 1024 blocks
    int v = i >> 10, ch = i & 1023;
    float s = ldf(bi0, ch, f32);
    for (int e = 0; e < 512; ++e)
        s += ldf(emb, (size_t)v * 512 + e, f32) * ldf(wi0, (size_t)ch * 512 + e, f32);
    etab[i] = s;
}

__global__ void c12_kernel(const void* __restrict__ pw, const void* __restrict__ g,
                           const void* __restrict__ be, const void* __restrict__ pb,
                           const unsigned* __restrict__ flag, float* __restrict__ c12) {
    const bool f32 = (*flag != 0);
    int v = threadIdx.x;                         // 1 block x 256
    float a = 0.f, b = 0.f;
    for (int k = 0; k < 1024; ++k) {
        float w = ldf(pw, (size_t)v * 1024 + k, f32);
        a += (float)(f16)(w * ldf(g, k, f32));
        b += w * ldf(be, k, f32);
    }
    c12[v] = a;
    c12[256 + v] = b + ldf(pb, v, f32);
}

// --------------------------- templated step loop ---------------------------
// FAST=true : group-private DATA via sc0 (XCD-local L2); BARRIER via sc0
//             arrival slots + parallel polling, timeout-guarded by an
//             always-published agent-scope counter (compose-safe fallback).
// FAST=false: R6 agent-scope (sc0|sc1, IF) path throughout.
template<bool FAST>
__device__ __forceinline__ void run_loop(
    const int role, const int rid, const int gbase,
    const int tid, const int lane, const int n, const int quad,
    const int ch, const int outv,
    const f16x8 (&wf)[32], const float bias, const float c1v, const float c2v,
    const bool f32io,
    const float* __restrict__ etab, const int* __restrict__ x,
    f16* __restrict__ h0buf, f16* __restrict__ h1buf, float* __restrict__ xpf,
    void* __restrict__ out, unsigned* __restrict__ myc,
    f16 (&As)[16][1032])
{
    for (int t = 0; t < NST; ++t) {
        bool active;
        f16* rbuf;
        if (role == 0)      { active = (t < 512);            rbuf = h0buf; }
        else if (role == 1) { active = (t >= 1 && t <= 512); rbuf = h0buf; }
        else if (role == 2) { active = (t >= 2 && t <= 513); rbuf = h1buf; }
        else                { active = (t >= 3 && t <= 514); rbuf = h1buf; }

        if (active) {   // block-uniform
            const f16* Abase = rbuf + ((t + 1) & 1) * (BATCH * HID)
                             + (size_t)gbase * HID;

            // epilogue operands (issued before staging so latency overlaps)
            float ev[4] = {0.f, 0.f, 0.f, 0.f};
            if (role == 0) {
#pragma unroll
                for (int r = 0; r < 4; ++r) {
                    int b = gbase + quad * 4 + r;
                    ev[r] = etab[(size_t)x[b * TSTEPS + t] * HID + ch];
                }
            } else if (role == 2) {
                const float* xs = xpf + (t & 1) * (BATCH * HID);
                if constexpr (FAST) {
                    const float* p0 = xs + (size_t)(gbase + quad * 4 + 0) * HID + ch;
                    const float* p1 = xs + (size_t)(gbase + quad * 4 + 1) * HID + ch;
                    const float* p2 = xs + (size_t)(gbase + quad * 4 + 2) * HID + ch;
                    const float* p3 = xs + (size_t)(gbase + quad * 4 + 3) * HID + ch;
                    asm volatile(
                        "global_load_dword %0, %4, off sc0\n\t"
                        "global_load_dword %1, %5, off sc0\n\t"
                        "global_load_dword %2, %6, off sc0\n\t"
                        "global_load_dword %3, %7, off sc0\n\t"
                        "s_waitcnt vmcnt(0)"
                        : "=&v"(ev[0]), "=&v"(ev[1]), "=&v"(ev[2]), "=&v"(ev[3])
                        : "v"(p0), "v"(p1), "v"(p2), "v"(p3)
                        : "memory");
                } else {
#pragma unroll
                    for (int r = 0; r < 4; ++r)
                        ev[r] = ldf4c(xs + (size_t)(gbase + quad * 4 + r) * HID + ch);
                }
            }

            // ---- cooperative A-tile stage: 32 KB, once per block ----
            if constexpr (FAST) {
                const f16* ga[4]; f16* da[4];
#pragma unroll
                for (int it = 0; it < 4; ++it) {
                    int idx = it * 512 + tid;        // 2048 chunks of 16B
                    int row = idx >> 7, col = (idx & 127) << 3;
                    ga[it] = Abase + (size_t)row * HID + col;
                    da[it] = &As[row][col];
                }
                f32x4 v0, v1, v2, v3;
                asm volatile(
                    "global_load_dwordx4 %0, %4, off sc0\n\t"
                    "global_load_dwordx4 %1, %5, off sc0\n\t"
                    "global_load_dwordx4 %2, %6, off sc0\n\t"
                    "global_load_dwordx4 %3, %7, off sc0\n\t"
                    "s_waitcnt vmcnt(0)"
                    : "=&v"(v0), "=&v"(v1), "=&v"(v2), "=&v"(v3)
                    : "v"(ga[0]), "v"(ga[1]), "v"(ga[2]), "v"(ga[3])
                    : "memory");
                *(f32x4*)da[0] = v0;
                *(f32x4*)da[1] = v1;
                *(f32x4*)da[2] = v2;
                *(f32x4*)da[3] = v3;
            } else {
#pragma unroll
                for (int it = 0; it < 4; ++it) {
                    int idx = it * 512 + tid;
                    int row = idx >> 7, col = (idx & 127) << 3;
                    f16x8 v = lda16(Abase + (size_t)row * HID + col);
                    *(f16x8*)&As[row][col] = v;
                }
            }

            __syncthreads();    // A-tile visible to all waves

            float mu = 0.f, rs = 0.f;
            if (role == 3) {    // LN stats from the LDS copy
                const f16* srow = &As[n][quad * 256];
                float sum = 0.f, sq = 0.f;
#pragma unroll
                for (int i = 0; i < 256; i += 8) {
                    f16x8 hv = *(const f16x8*)(srow + i);
#pragma unroll
                    for (int j = 0; j < 8; ++j) {
                        float e = (float)hv[j];
                        sum += e; sq += e * e;
                    }
                }
                sum += __shfl_xor(sum, 16); sq += __shfl_xor(sq, 16);
                sum += __shfl_xor(sum, 32); sq += __shfl_xor(sq, 32);
                mu = sum * (1.f / 1024.f);
                float var = sq * (1.f / 1024.f) - mu * mu;
                rs = rsqrtf(fmaxf(var, 0.f) + 1e-5f);
            }

            const f16* arow = &As[n][quad * 8];
            f32x4 a0 = {0,0,0,0}, a1 = {0,0,0,0}, a2 = {0,0,0,0}, a3 = {0,0,0,0};
#pragma unroll
            for (int kt = 0; kt < 32; kt += 4) {
                a0 = mfma16(*(const f16x8*)(arow + (kt + 0) * 32), wf[kt + 0], a0);
                a1 = mfma16(*(const f16x8*)(arow + (kt + 1) * 32), wf[kt + 1], a1);
                a2 = mfma16(*(const f16x8*)(arow + (kt + 2) * 32), wf[kt + 2], a2);
                a3 = mfma16(*(const f16x8*)(arow + (kt + 3) * 32), wf[kt + 3], a3);
            }
            f32x4 acc = (a0 + a1) + (a2 + a3);

            if (role == 0 || role == 2) {
                f16* dw = ((role == 0) ? h0buf : h1buf) + (t & 1) * (BATCH * HID);
                if constexpr (FAST) {
                    unsigned u0 = f16bits32((f16)tanhf(acc[0] + ev[0]));
                    unsigned u1 = f16bits32((f16)tanhf(acc[1] + ev[1]));
                    unsigned u2 = f16bits32((f16)tanhf(acc[2] + ev[2]));
                    unsigned u3 = f16bits32((f16)tanhf(acc[3] + ev[3]));
                    f16* q0 = dw + (size_t)(gbase + quad * 4 + 0) * HID + ch;
                    f16* q1 = dw + (size_t)(gbase + quad * 4 + 1) * HID + ch;
                    f16* q2 = dw + (size_t)(gbase + quad * 4 + 2) * HID + ch;
                    f16* q3 = dw + (size_t)(gbase + quad * 4 + 3) * HID + ch;
                    // in-asm vmcnt(0): stores acked at XCD L2 BEFORE this wave
                    // reaches the barrier arrival store.
                    asm volatile(
                        "global_store_short %4, %0, off sc0\n\t"
                        "global_store_short %5, %1, off sc0\n\t"
                        "global_store_short %6, %2, off sc0\n\t"
                        "global_store_short %7, %3, off sc0\n\t"
                        "s_waitcnt vmcnt(0)"
                        :: "v"(u0), "v"(u1), "v"(u2), "v"(u3),
                           "v"(q0), "v"(q1), "v"(q2), "v"(q3)
                        : "memory");
                } else {
#pragma unroll
                    for (int r = 0; r < 4; ++r) {
                        int b = gbase + quad * 4 + r;
                        sth2(dw + (size_t)b * HID + ch, (f16)tanhf(acc[r] + ev[r]));
                    }
                }
            } else if (role == 1) {
                float* dw = xpf + ((t + 1) & 1) * (BATCH * HID);
                if constexpr (FAST) {
                    float w0 = acc[0] + bias, w1 = acc[1] + bias;
                    float w2 = acc[2] + bias, w3 = acc[3] + bias;
                    float* q0 = dw + (size_t)(gbase + quad * 4 + 0) * HID + ch;
                    float* q1 = dw + (size_t)(gbase + quad * 4 + 1) * HID + ch;
                    float* q2 = dw + (size_t)(gbase + quad * 4 + 2) * HID + ch;
                    float* q3 = dw + (size_t)(gbase + quad * 4 + 3) * HID + ch;
                    asm volatile(
                        "global_store_dword %4, %0, off sc0\n\t"
                        "global_store_dword %5, %1, off sc0\n\t"
                        "global_store_dword %6, %2, off sc0\n\t"
                        "global_store_dword %7, %3, off sc0\n\t"
                        "s_waitcnt vmcnt(0)"
                        :: "v"(w0), "v"(w1), "v"(w2), "v"(w3),
                           "v"(q0), "v"(q1), "v"(q2), "v"(q3)
                        : "memory");
                } else {
#pragma unroll
                    for (int r = 0; r < 4; ++r) {
                        int b = gbase + quad * 4 + r;
                        stf4(dw + (size_t)b * HID + ch, acc[r] + bias);
                    }
                }
            } else {
                int s = t - 3;
#pragma unroll
                for (int r = 0; r < 4; ++r) {
                    int m = quad * 4 + r;
                    float mm = __shfl(mu, m), rr = __shfl(rs, m);
                    float lv = rr * acc[r] - rr * mm * c1v + c2v;
                    size_t oi = ((size_t)(gbase + m) * TSTEPS + s) * 256 + outv;
                    if (f32io) ((float*)out)[oi] = lv;
                    else       ((bf16*)out)[oi]  = (bf16)lv;
                }
            }
        }

        // ---- per-group barrier (26 blocks) ----
        __syncthreads();    // all waves' data stores drained
        if constexpr (FAST) {
            const unsigned want = (unsigned)(t + 1);
            if (tid < 64) {      // wave 0
                if (lane == 0) {
                    unsigned* ms = myc + rid;
                    asm volatile(
                        "global_store_dword %0, %1, off sc0\n\t"
                        "s_waitcnt vmcnt(0)"
                        :: "v"(ms), "v"(want) : "memory");
                }
                // fast spin: parallel sc0 polls of all 26 slots (XCD L2)
                const unsigned* sp = myc + lane;   // lanes >=26 masked below
                bool done = false;
                for (int it = 0; it < FAST_SPIN_MAX; ++it) {
                    unsigned v;
                    asm volatile(
                        "global_load_dword %0, %1, off sc0\n\t"
                        "s_waitcnt vmcnt(0)"
                        : "=&v"(v) : "v"(sp) : "memory");
                    if (__all((lane >= 26) || (v >= want))) { done = true; break; }
                    __builtin_amdgcn_s_sleep(1);
                }
                // UNCONDITIONAL agent-scope publish (exactly once per step):
                // keeps the fallback counter live for any timeout observer.
                if (lane == 0)
                    __hip_atomic_fetch_add(myc + 31, 1u, __ATOMIC_RELAXED,
                                           __HIP_MEMORY_SCOPE_AGENT);
                if (!done && lane == 0) {
                    // fallback: R6-proven agent-scope counter spin
                    const unsigned tgt = 26u * want;
                    while (__hip_atomic_load(myc + 31, __ATOMIC_RELAXED,
                                             __HIP_MEMORY_SCOPE_AGENT) < tgt)
                        __builtin_amdgcn_s_sleep(1);
                }
            }
        } else {
            if (tid == 0) {
                __hip_atomic_fetch_add(myc, 1u, __ATOMIC_RELAXED, __HIP_MEMORY_SCOPE_AGENT);
                const unsigned tgt = 26u * (unsigned)(t + 1);
                while (__hip_atomic_load(myc, __ATOMIC_RELAXED, __HIP_MEMORY_SCOPE_AGENT) < tgt)
                    __builtin_amdgcn_s_sleep(1);
            }
        }
        __syncthreads();
    }
}

// --------------------------- persistent mega kernel ------------------------
// grid 208 = 8 groups x 26 blocks; 512 thr (8 waves).
// rid = bid>>3: 0-7 L0, 8-15 XP, 16-23 L1, 24-25 PR.
__global__ __launch_bounds__(512, 2) void mega_kernel(
    const void* __restrict__ wh0, const void* __restrict__ wi1,
    const void* __restrict__ wh1, const void* __restrict__ pw,
    const void* __restrict__ lng, const void* __restrict__ bi1,
    const float* __restrict__ etab, const float* __restrict__ c12,
    const int* __restrict__ x, const unsigned* __restrict__ flag,
    f16* __restrict__ h0buf, f16* __restrict__ h1buf, float* __restrict__ xpf,
    void* __restrict__ out, unsigned* __restrict__ cnt)
{
    const bool f32io = (*flag != 0);
    const int bid  = blockIdx.x;
    const int g    = bid & 7, rid = bid >> 3;
    const int role = rid >> 3;                   // 0 L0, 1 XP, 2 L1, 3 PR
    const int slice = rid & 7;
    const int tid  = threadIdx.x;
    const int wave = tid >> 6, lane = tid & 63;
    const int n    = lane & 15, quad = lane >> 4;
    const int gbase = g * 16;
    // FAST: cnt[g*32 + 0..25] arrival slots, cnt[g*32+31] fallback counter.
    // SLOW: cnt[g*32] group counter. Regions disjoint across groups.
    unsigned* const myc = cnt + g * 32;

    // A-tile staging buffer: 16 rows x 1032 (stride 516 dwords -> uniform
    // 8 dwords/bank for all b128 patterns, the wave64 minimum). 33 KB LDS.
    __shared__ __align__(16) f16 As[16][1032];

    // stationary f16 weight fragments: 32 x f16x8 = 128 VGPR
    f16x8 wf[32];
    float bias = 0.f, c1v = 0.f, c2v = 0.f;
    int ch = 0, outv = 0;
    if (role < 3) {
        ch = slice * 128 + wave * 16 + n;
        const void* W = (role == 0) ? wh0 : ((role == 1) ? wi1 : wh1);
#pragma unroll
        for (int kt = 0; kt < 32; ++kt) {
            f16x8 t;
#pragma unroll
            for (int j = 0; j < 8; ++j)
                t[j] = (f16)ldf(W, (size_t)ch * HID + kt * 32 + quad * 8 + j, f32io);
            wf[kt] = t;
        }
        if (role == 1) bias = ldf(bi1, ch, f32io);
    } else {
        int tile = slice * 8 + wave;             // 0..15
        outv = tile * 16 + n;
#pragma unroll
        for (int kt = 0; kt < 32; ++kt) {
            f16x8 t;
#pragma unroll
            for (int j = 0; j < 8; ++j) {
                int k = kt * 32 + quad * 8 + j;
                t[j] = (f16)(ldf(pw, (size_t)outv * HID + k, f32io) * ldf(lng, k, f32io));
            }
            wf[kt] = t;
        }
        c1v = c12[outv];
        c2v = c12[256 + outv];
    }

    // ---- XCD-uniformity detection (agent-scope; once) ----
    // Slots cnt[256+bid] hold 0x100|xcc after publish; memset zeroed them.
    // Publish-then-wait over co-resident blocks (same premise as the main
    // barrier, proven over 515 steps in R6/R8) -> cannot deadlock.
    unsigned xcc = 0;
    asm volatile("s_getreg_b32 %0, hwreg(HW_REG_XCC_ID)" : "=s"(xcc));
    xcc &= 0xFu;
    __shared__ int fsh;
    if (tid == 0) {
        const unsigned my = 0x100u | xcc;
        __hip_atomic_store(cnt + 256 + bid, my, __ATOMIC_RELAXED, __HIP_MEMORY_SCOPE_AGENT);
        int ok = 1;
        for (int r = 0; r < 26; ++r) {
            unsigned v;
            for (;;) {
                v = __hip_atomic_load(cnt + 256 + g + 8 * r, __ATOMIC_RELAXED, __HIP_MEMORY_SCOPE_AGENT);
                if (v & 0x100u) break;
                __builtin_amdgcn_s_sleep(2);
            }
            if (v != my) ok = 0;
        }
        fsh = ok;
    }
    __syncthreads();
    const bool fast = (fsh != 0);

    if (fast)
        run_loop<true >(role, rid, gbase, tid, lane, n, quad, ch, outv, wf, bias, c1v, c2v,
                        f32io, etab, x, h0buf, h1buf, xpf, out, myc, As);
    else
        run_loop<false>(role, rid, gbase, tid, lane, n, quad, ch, outv, wf, bias, c1v, c2v,
                        f32io, etab, x, h0buf, h1buf, xpf, out, myc, As);
}

// --------------------------- launch -----------------------------------------
extern "C" void kernel_launch(void* const* d_in, const int* in_sizes, int n_in,
                              void* d_out, int out_size, void* d_ws, size_t ws_size,
                              hipStream_t stream) {
    const void* emb    = d_in[0];
    const void* wi0    = d_in[1];
    const void* bi0    = d_in[2];
    const void* wh0    = d_in[3];
    const void* wi1    = d_in[4];
    const void* bi1    = d_in[5];
    const void* wh1    = d_in[6];
    const void* ln_g   = d_in[7];
    const void* ln_b   = d_in[8];
    const void* proj_w = d_in[9];
    const void* proj_b = d_in[10];
    const int*  x      = (const int*)d_in[11];
    char* ws = (char*)d_ws;

    // ws map (bytes), total 3,151,936
    float*    etab  = (float*)(ws + 0);             // 1,048,576
    float*    c12   = (float*)(ws + 1048576);       // 2,048
    unsigned* flag  = (unsigned*)(ws + 1050624);    // 64
    f16*      h0buf = (f16*)(ws + 1050688);         // 524,288 ping-pong
    f16*      h1buf = (f16*)(ws + 1574976);         // 524,288 ping-pong
    float*    xpf   = (float*)(ws + 2099264);       // 1,048,576 ping-pong
    unsigned* cnt   = (unsigned*)(ws + 3147840);    // 4,096 (barrier slots + xcd slots)
    if (ws_size < 3151936u) return;  // bail signature: out stays 0

    // zero flag + h/xp ping-pongs + counters/slots: [1050624, 3151936)
    hipMemsetAsync(ws + 1050624, 0, 3151936 - 1050624, stream);

    det_kernel<<<1, 256, 0, stream>>>((const unsigned short*)emb, flag);
    etab_kernel<<<1024, 256, 0, stream>>>(emb, wi0, bi0, flag, etab);
    c12_kernel<<<1, 256, 0, stream>>>(proj_w, ln_g, ln_b, proj_b, flag, c12);
    mega_kernel<<<208, 512, 0, stream>>>(wh0, wi1, wh1, proj_w, ln_g, bi1,
                                         etab, c12, x, flag,
                                         h0buf, h1buf, xpf, d_out, cnt);
}

// Round 6
// 3360.506 us; speedup vs baseline: 2.8624x; 2.8624x over previous
//
#include <hip/hip_runtime.h>
#include <hip/hip_bf16.h>

// ---------------------------------------------------------------------------
// 2-layer tanh RNN (B=128, T=512, H=1024) + LN + vocab projection.
// Persistent fused pipeline, weight-stationary f16 fragments in VGPRs,
// per-group (16 batch rows) spin barriers.
//
//   L0 : h0[t]   = tanh(etab[x[:,t]] + Wh0·h0[t-1])        t in [0,512)
//   XP : xp[t-1] = wi1·h0[t-1] + bi1                        t in [1,512]
//   L1 : h1[t-2] = tanh(xp[t-2] + Wh1·h1[t-3])             t in [2,513]
//   PR : out[t-3] = algebraic-LN(h1[t-3]) @ (g*pw)^T + c    t in [3,514]
//
// R11->R12: AGENT-SCOPE POLLS ON XCD-LOCAL SLOTS. R11's diagnostic proved
// the sc0-only spin load hits a STALE L1 LINE forever (measured ~94ns/poll
// = L1-hit rate; every step timed out into the fallback): on gfx950 sc0
// global_load does not bypass/invalidate an existing L1 line. (R8's sc0
// DATA path works only because 32KB/step staging thrashes the 32KB L1;
// R7/R9 hung on the same stale-L1 blindness with no timeout.)
// Fix: arrival stays an sc0 STORE (slot line lands DIRTY in this XCD's L2;
// all 26 blocks verified on this XCD), but the spin uses agent-scope loads
// (sc0|sc1 -- the load type PROVEN to observe remote updates, R6/R8/R11
// SLOW+fallback). Coherence serves them from the local dirty L2 line
// (~200-300cy) instead of IF (~900cy); lanes 0..25 observe all 26 slots in
// parallel. Timeout (64 polls) + unconditional agent publish + fallback
// spin retained: a wrong premise yields a PASSING slow run, never a hang.
//
// R8-proven and unchanged: XCD-local sc0 DATA path (A-tile stage, xp loads,
// h/xp stores -> FETCH 329->67 MB, WRITE 603->81 MB), XCC_ID-uniformity
// detection (FAST only if all 26 blocks of the group share one XCD),
// agent-scope SLOW path for non-uniform groups.
//
// LDS note: As row stride 516 dwords gives the uniform-minimum 8 dwords/bank
// for all wave64 b128 patterns; SQ_LDS_BANK_CONFLICT ~1.09e8 is intrinsic.
//
// INPUT DTYPE DETECTED AT RUNTIME (bf16 vs fp32), flag steers all I/O.
// ws need: 3.01 MB.
// ---------------------------------------------------------------------------

typedef __bf16 bf16;
typedef _Float16 f16;
typedef _Float16 f16x8 __attribute__((ext_vector_type(8)));
typedef float f32x4 __attribute__((ext_vector_type(4)));
typedef unsigned long long u64;

#define TSTEPS 512
#define BATCH  128
#define HID    1024
#define NST    515
#define FAST_SPIN_MAX 64

__device__ __forceinline__ f32x4 mfma16(f16x8 a, f16x8 b, f32x4 c) {
    return __builtin_amdgcn_mfma_f32_16x16x32_f16(a, b, c, 0, 0, 0);
}

// ---- agent-coherent (sc0|sc1, L1/L2-bypassing) helpers (SLOW path) ----
__device__ __forceinline__ f16x8 lda16(const f16* p) {   // 16B via 2x8B
    union { u64 u[2]; f16x8 v; } c;
    c.u[0] = __hip_atomic_load((const u64*)p,     __ATOMIC_RELAXED, __HIP_MEMORY_SCOPE_AGENT);
    c.u[1] = __hip_atomic_load((const u64*)p + 1, __ATOMIC_RELAXED, __HIP_MEMORY_SCOPE_AGENT);
    return c.v;
}
__device__ __forceinline__ void sth2(f16* p, f16 v) {    // 2B coherent store
    union { f16 f; unsigned short s; } c; c.f = v;
    __hip_atomic_store((unsigned short*)p, c.s, __ATOMIC_RELAXED, __HIP_MEMORY_SCOPE_AGENT);
}
__device__ __forceinline__ void stf4(float* p, float v) { // 4B coherent store
    union { float f; unsigned u; } c; c.f = v;
    __hip_atomic_store((unsigned*)p, c.u, __ATOMIC_RELAXED, __HIP_MEMORY_SCOPE_AGENT);
}
__device__ __forceinline__ float ldf4c(const float* p) {  // 4B coherent load
    union { float f; unsigned u; } c;
    c.u = __hip_atomic_load((const unsigned*)p, __ATOMIC_RELAXED, __HIP_MEMORY_SCOPE_AGENT);
    return c.f;
}

__device__ __forceinline__ unsigned f16bits32(f16 v) {
    union { f16 f; unsigned short s; } c; c.f = v; return (unsigned)c.s;
}

// dual-dtype scalar load (read-only inputs, plain cached)
__device__ __forceinline__ float ldf(const void* p, size_t i, bool f32) {
    return f32 ? ((const float*)p)[i] : (float)((const bf16*)p)[i];
}

// --------------------------- dtype detector --------------------------------
__global__ void det_kernel(const unsigned short* __restrict__ e, unsigned* __restrict__ flag) {
    int tid = threadIdx.x;                       // 1 block x 256
    int cnt = 0;
    for (int i = tid; i < 1024; i += 256) {
        unsigned short u = e[i];
        int ex = (u >> 7) & 0xFF;
        if ((ex >= 110 && ex <= 131) || u == 0) cnt++;
    }
    __shared__ int sh[256];
    sh[tid] = cnt; __syncthreads();
    for (int s = 128; s > 0; s >>= 1) { if (tid < s) sh[tid] += sh[tid + s]; __syncthreads(); }
    if (tid == 0) *flag = (sh[0] >= 768) ? 0u : 1u;
}

// --------------------------- setup kernels ---------------------------------
__global__ void etab_kernel(const void* __restrict__ emb, const void* __restrict__ wi0,
                            const void* __restrict__ bi0, const unsigned* __restrict__ flag,
                            float* __restrict__ etab) {
    const bool f32 = (*flag != 0);
    int i = blockIdx.x * 256 + threadIdx.x;      // 1024 blocks
    int v = i >> 10, ch = i & 1023;
    float s = ldf(bi0, ch, f32);
    for (int e = 0; e < 512; ++e)
        s += ldf(emb, (size_t)v * 512 + e, f32) * ldf(wi0, (size_t)ch * 512 + e, f32);
    etab[i] = s;
}

__global__ void c12_kernel(const void* __restrict__ pw, const void* __restrict__ g,
                           const void* __restrict__ be, const void* __restrict__ pb,
                           const unsigned* __restrict__ flag, float* __restrict__ c12) {
    const bool f32 = (*flag != 0);
    int v = threadIdx.x;                         // 1 block x 256
    float a = 0.f, b = 0.f;
    for (int k = 0; k < 1024; ++k) {
        float w = ldf(pw, (size_t)v * 1024 + k, f32);
        a += (float)(f16)(w * ldf(g, k, f32));
        b += w * ldf(be, k, f32);
    }
    c12[v] = a;
    c12[256 + v] = b + ldf(pb, v, f32);
}

// --------------------------- templated step loop ---------------------------
// FAST=true : group-private DATA via sc0 (XCD-local L2); BARRIER via sc0
//             arrival slots (dirty in local L2) + parallel AGENT-scope
//             polls, timeout-guarded by an always-published agent counter.
// FAST=false: R6 agent-scope (sc0|sc1, IF) path throughout.
template<bool FAST>
__device__ __forceinline__ void run_loop(
    const int role, const int rid, const int gbase,
    const int tid, const int lane, const int n, const int quad,
    const int ch, const int outv,
    const f16x8 (&wf)[32], const float bias, const float c1v, const float c2v,
    const bool f32io,
    const float* __restrict__ etab, const int* __restrict__ x,
    f16* __restrict__ h0buf, f16* __restrict__ h1buf, float* __restrict__ xpf,
    void* __restrict__ out, unsigned* __restrict__ myc,
    f16 (&As)[16][1032])
{
    for (int t = 0; t < NST; ++t) {
        bool active;
        f16* rbuf;
        if (role == 0)      { active = (t < 512);            rbuf = h0buf; }
        else if (role == 1) { active = (t >= 1 && t <= 512); rbuf = h0buf; }
        else if (role == 2) { active = (t >= 2 && t <= 513); rbuf = h1buf; }
        else                { active = (t >= 3 && t <= 514); rbuf = h1buf; }

        if (active) {   // block-uniform
            const f16* Abase = rbuf + ((t + 1) & 1) * (BATCH * HID)
                             + (size_t)gbase * HID;

            // epilogue operands (issued before staging so latency overlaps)
            float ev[4] = {0.f, 0.f, 0.f, 0.f};
            if (role == 0) {
#pragma unroll
                for (int r = 0; r < 4; ++r) {
                    int b = gbase + quad * 4 + r;
                    ev[r] = etab[(size_t)x[b * TSTEPS + t] * HID + ch];
                }
            } else if (role == 2) {
                const float* xs = xpf + (t & 1) * (BATCH * HID);
                if constexpr (FAST) {
                    const float* p0 = xs + (size_t)(gbase + quad * 4 + 0) * HID + ch;
                    const float* p1 = xs + (size_t)(gbase + quad * 4 + 1) * HID + ch;
                    const float* p2 = xs + (size_t)(gbase + quad * 4 + 2) * HID + ch;
                    const float* p3 = xs + (size_t)(gbase + quad * 4 + 3) * HID + ch;
                    asm volatile(
                        "global_load_dword %0, %4, off sc0\n\t"
                        "global_load_dword %1, %5, off sc0\n\t"
                        "global_load_dword %2, %6, off sc0\n\t"
                        "global_load_dword %3, %7, off sc0\n\t"
                        "s_waitcnt vmcnt(0)"
                        : "=&v"(ev[0]), "=&v"(ev[1]), "=&v"(ev[2]), "=&v"(ev[3])
                        : "v"(p0), "v"(p1), "v"(p2), "v"(p3)
                        : "memory");
                } else {
#pragma unroll
                    for (int r = 0; r < 4; ++r)
                        ev[r] = ldf4c(xs + (size_t)(gbase + quad * 4 + r) * HID + ch);
                }
            }

            // ---- cooperative A-tile stage: 32 KB, once per block ----
            if constexpr (FAST) {
                const f16* ga[4]; f16* da[4];
#pragma unroll
                for (int it = 0; it < 4; ++it) {
                    int idx = it * 512 + tid;        // 2048 chunks of 16B
                    int row = idx >> 7, col = (idx & 127) << 3;
                    ga[it] = Abase + (size_t)row * HID + col;
                    da[it] = &As[row][col];
                }
                f32x4 v0, v1, v2, v3;
                asm volatile(
                    "global_load_dwordx4 %0, %4, off sc0\n\t"
                    "global_load_dwordx4 %1, %5, off sc0\n\t"
                    "global_load_dwordx4 %2, %6, off sc0\n\t"
                    "global_load_dwordx4 %3, %7, off sc0\n\t"
                    "s_waitcnt vmcnt(0)"
                    : "=&v"(v0), "=&v"(v1), "=&v"(v2), "=&v"(v3)
                    : "v"(ga[0]), "v"(ga[1]), "v"(ga[2]), "v"(ga[3])
                    : "memory");
                *(f32x4*)da[0] = v0;
                *(f32x4*)da[1] = v1;
                *(f32x4*)da[2] = v2;
                *(f32x4*)da[3] = v3;
            } else {
#pragma unroll
                for (int it = 0; it < 4; ++it) {
                    int idx = it * 512 + tid;
                    int row = idx >> 7, col = (idx & 127) << 3;
                    f16x8 v = lda16(Abase + (size_t)row * HID + col);
                    *(f16x8*)&As[row][col] = v;
                }
            }

            __syncthreads();    // A-tile visible to all waves

            float mu = 0.f, rs = 0.f;
            if (role == 3) {    // LN stats from the LDS copy
                const f16* srow = &As[n][quad * 256];
                float sum = 0.f, sq = 0.f;
#pragma unroll
                for (int i = 0; i < 256; i += 8) {
                    f16x8 hv = *(const f16x8*)(srow + i);
#pragma unroll
                    for (int j = 0; j < 8; ++j) {
                        float e = (float)hv[j];
                        sum += e; sq += e * e;
                    }
                }
                sum += __shfl_xor(sum, 16); sq += __shfl_xor(sq, 16);
                sum += __shfl_xor(sum, 32); sq += __shfl_xor(sq, 32);
                mu = sum * (1.f / 1024.f);
                float var = sq * (1.f / 1024.f) - mu * mu;
                rs = rsqrtf(fmaxf(var, 0.f) + 1e-5f);
            }

            const f16* arow = &As[n][quad * 8];
            f32x4 a0 = {0,0,0,0}, a1 = {0,0,0,0}, a2 = {0,0,0,0}, a3 = {0,0,0,0};
#pragma unroll
            for (int kt = 0; kt < 32; kt += 4) {
                a0 = mfma16(*(const f16x8*)(arow + (kt + 0) * 32), wf[kt + 0], a0);
                a1 = mfma16(*(const f16x8*)(arow + (kt + 1) * 32), wf[kt + 1], a1);
                a2 = mfma16(*(const f16x8*)(arow + (kt + 2) * 32), wf[kt + 2], a2);
                a3 = mfma16(*(const f16x8*)(arow + (kt + 3) * 32), wf[kt + 3], a3);
            }
            f32x4 acc = (a0 + a1) + (a2 + a3);

            if (role == 0 || role == 2) {
                f16* dw = ((role == 0) ? h0buf : h1buf) + (t & 1) * (BATCH * HID);
                if constexpr (FAST) {
                    unsigned u0 = f16bits32((f16)tanhf(acc[0] + ev[0]));
                    unsigned u1 = f16bits32((f16)tanhf(acc[1] + ev[1]));
                    unsigned u2 = f16bits32((f16)tanhf(acc[2] + ev[2]));
                    unsigned u3 = f16bits32((f16)tanhf(acc[3] + ev[3]));
                    f16* q0 = dw + (size_t)(gbase + quad * 4 + 0) * HID + ch;
                    f16* q1 = dw + (size_t)(gbase + quad * 4 + 1) * HID + ch;
                    f16* q2 = dw + (size_t)(gbase + quad * 4 + 2) * HID + ch;
                    f16* q3 = dw + (size_t)(gbase + quad * 4 + 3) * HID + ch;
                    // in-asm vmcnt(0): stores acked at XCD L2 BEFORE this wave
                    // reaches the barrier arrival store.
                    asm volatile(
                        "global_store_short %4, %0, off sc0\n\t"
                        "global_store_short %5, %1, off sc0\n\t"
                        "global_store_short %6, %2, off sc0\n\t"
                        "global_store_short %7, %3, off sc0\n\t"
                        "s_waitcnt vmcnt(0)"
                        :: "v"(u0), "v"(u1), "v"(u2), "v"(u3),
                           "v"(q0), "v"(q1), "v"(q2), "v"(q3)
                        : "memory");
                } else {
#pragma unroll
                    for (int r = 0; r < 4; ++r) {
                        int b = gbase + quad * 4 + r;
                        sth2(dw + (size_t)b * HID + ch, (f16)tanhf(acc[r] + ev[r]));
                    }
                }
            } else if (role == 1) {
                float* dw = xpf + ((t + 1) & 1) * (BATCH * HID);
                if constexpr (FAST) {
                    float w0 = acc[0] + bias, w1 = acc[1] + bias;
                    float w2 = acc[2] + bias, w3 = acc[3] + bias;
                    float* q0 = dw + (size_t)(gbase + quad * 4 + 0) * HID + ch;
                    float* q1 = dw + (size_t)(gbase + quad * 4 + 1) * HID + ch;
                    float* q2 = dw + (size_t)(gbase + quad * 4 + 2) * HID + ch;
                    float* q3 = dw + (size_t)(gbase + quad * 4 + 3) * HID + ch;
                    asm volatile(
                        "global_store_dword %4, %0, off sc0\n\t"
                        "global_store_dword %5, %1, off sc0\n\t"
                        "global_store_dword %6, %2, off sc0\n\t"
                        "global_store_dword %7, %3, off sc0\n\t"
                        "s_waitcnt vmcnt(0)"
                        :: "v"(w0), "v"(w1), "v"(w2), "v"(w3),
                           "v"(q0), "v"(q1), "v"(q2), "v"(q3)
                        : "memory");
                } else {
#pragma unroll
                    for (int r = 0; r < 4; ++r) {
                        int b = gbase + quad * 4 + r;
                        stf4(dw + (size_t)b * HID + ch, acc[r] + bias);
                    }
                }
            } else {
                int s = t - 3;
#pragma unroll
                for (int r = 0; r < 4; ++r) {
                    int m = quad * 4 + r;
                    float mm = __shfl(mu, m), rr = __shfl(rs, m);
                    float lv = rr * acc[r] - rr * mm * c1v + c2v;
                    size_t oi = ((size_t)(gbase + m) * TSTEPS + s) * 256 + outv;
                    if (f32io) ((float*)out)[oi] = lv;
                    else       ((bf16*)out)[oi]  = (bf16)lv;
                }
            }
        }

        // ---- per-group barrier (26 blocks) ----
        __syncthreads();    // all waves' data stores drained
        if constexpr (FAST) {
            const unsigned want = (unsigned)(t + 1);
            if (tid < 64) {      // wave 0
                if (lane == 0) {
                    unsigned* ms = myc + rid;
                    asm volatile(
                        "global_store_dword %0, %1, off sc0\n\t"
                        "s_waitcnt vmcnt(0)"
                        :: "v"(ms), "v"(want) : "memory");
                }
                // fast spin: parallel AGENT-scope polls (true L1 bypass;
                // served by the local XCD L2 where the sc0 arrival stores
                // land dirty). R11 proved sc0-only polls read stale L1.
                const unsigned* sp = myc + lane;
                bool done = false;
                for (int it = 0; it < FAST_SPIN_MAX; ++it) {
                    unsigned v = (lane < 26)
                        ? __hip_atomic_load(sp, __ATOMIC_RELAXED, __HIP_MEMORY_SCOPE_AGENT)
                        : want;
                    if (__all(v >= want)) { done = true; break; }
                    __builtin_amdgcn_s_sleep(1);
                }
                // UNCONDITIONAL agent-scope publish (exactly once per step):
                // keeps the fallback counter live for any timeout observer.
                if (lane == 0)
                    __hip_atomic_fetch_add(myc + 31, 1u, __ATOMIC_RELAXED,
                                           __HIP_MEMORY_SCOPE_AGENT);
                if (!done && lane == 0) {
                    // fallback: R6-proven agent-scope counter spin
                    const unsigned tgt = 26u * want;
                    while (__hip_atomic_load(myc + 31, __ATOMIC_RELAXED,
                                             __HIP_MEMORY_SCOPE_AGENT) < tgt)
                        __builtin_amdgcn_s_sleep(1);
                }
            }
        } else {
            if (tid == 0) {
                __hip_atomic_fetch_add(myc, 1u, __ATOMIC_RELAXED, __HIP_MEMORY_SCOPE_AGENT);
                const unsigned tgt = 26u * (unsigned)(t + 1);
                while (__hip_atomic_load(myc, __ATOMIC_RELAXED, __HIP_MEMORY_SCOPE_AGENT) < tgt)
                    __builtin_amdgcn_s_sleep(1);
            }
        }
        __syncthreads();
    }
}

// --------------------------- persistent mega kernel ------------------------
// grid 208 = 8 groups x 26 blocks; 512 thr (8 waves).
// rid = bid>>3: 0-7 L0, 8-15 XP, 16-23 L1, 24-25 PR.
__global__ __launch_bounds__(512, 2) void mega_kernel(
    const void* __restrict__ wh0, const void* __restrict__ wi1,
    const void* __restrict__ wh1, const void* __restrict__ pw,
    const void* __restrict__ lng, const void* __restrict__ bi1,
    const float* __restrict__ etab, const float* __restrict__ c12,
    const int* __restrict__ x, const unsigned* __restrict__ flag,
    f16* __restrict__ h0buf, f16* __restrict__ h1buf, float* __restrict__ xpf,
    void* __restrict__ out, unsigned* __restrict__ cnt)
{
    const bool f32io = (*flag != 0);
    const int bid  = blockIdx.x;
    const int g    = bid & 7, rid = bid >> 3;
    const int role = rid >> 3;                   // 0 L0, 1 XP, 2 L1, 3 PR
    const int slice = rid & 7;
    const int tid  = threadIdx.x;
    const int wave = tid >> 6, lane = tid & 63;
    const int n    = lane & 15, quad = lane >> 4;
    const int gbase = g * 16;
    // FAST: cnt[g*32 + 0..25] arrival slots, cnt[g*32+31] fallback counter.
    // SLOW: cnt[g*32] group counter. Regions disjoint across groups.
    unsigned* const myc = cnt + g * 32;

    // A-tile staging buffer: 16 rows x 1032 (stride 516 dwords -> uniform
    // 8 dwords/bank for all b128 patterns, the wave64 minimum). 33 KB LDS.
    __shared__ __align__(16) f16 As[16][1032];

    // stationary f16 weight fragments: 32 x f16x8 = 128 VGPR
    f16x8 wf[32];
    float bias = 0.f, c1v = 0.f, c2v = 0.f;
    int ch = 0, outv = 0;
    if (role < 3) {
        ch = slice * 128 + wave * 16 + n;
        const void* W = (role == 0) ? wh0 : ((role == 1) ? wi1 : wh1);
#pragma unroll
        for (int kt = 0; kt < 32; ++kt) {
            f16x8 t;
#pragma unroll
            for (int j = 0; j < 8; ++j)
                t[j] = (f16)ldf(W, (size_t)ch * HID + kt * 32 + quad * 8 + j, f32io);
            wf[kt] = t;
        }
        if (role == 1) bias = ldf(bi1, ch, f32io);
    } else {
        int tile = slice * 8 + wave;             // 0..15
        outv = tile * 16 + n;
#pragma unroll
        for (int kt = 0; kt < 32; ++kt) {
            f16x8 t;
#pragma unroll
            for (int j = 0; j < 8; ++j) {
                int k = kt * 32 + quad * 8 + j;
                t[j] = (f16)(ldf(pw, (size_t)outv * HID + k, f32io) * ldf(lng, k, f32io));
            }
            wf[kt] = t;
        }
        c1v = c12[outv];
        c2v = c12[256 + outv];
    }

    // ---- XCD-uniformity detection (agent-scope; once) ----
    // Slots cnt[256+bid] hold 0x100|xcc after publish; memset zeroed them.
    // Publish-then-wait over co-resident blocks (same premise as the main
    // barrier, proven over 515 steps in R6/R8/R11) -> cannot deadlock.
    unsigned xcc = 0;
    asm volatile("s_getreg_b32 %0, hwreg(HW_REG_XCC_ID)" : "=s"(xcc));
    xcc &= 0xFu;
    __shared__ int fsh;
    if (tid == 0) {
        const unsigned my = 0x100u | xcc;
        __hip_atomic_store(cnt + 256 + bid, my, __ATOMIC_RELAXED, __HIP_MEMORY_SCOPE_AGENT);
        int ok = 1;
        for (int r = 0; r < 26; ++r) {
            unsigned v;
            for (;;) {
                v = __hip_atomic_load(cnt + 256 + g + 8 * r, __ATOMIC_RELAXED, __HIP_MEMORY_SCOPE_AGENT);
                if (v & 0x100u) break;
                __builtin_amdgcn_s_sleep(2);
            }
            if (v != my) ok = 0;
        }
        fsh = ok;
    }
    __syncthreads();
    const bool fast = (fsh != 0);

    if (fast)
        run_loop<true >(role, rid, gbase, tid, lane, n, quad, ch, outv, wf, bias, c1v, c2v,
                        f32io, etab, x, h0buf, h1buf, xpf, out, myc, As);
    else
        run_loop<false>(role, rid, gbase, tid, lane, n, quad, ch, outv, wf, bias, c1v, c2v,
                        f32io, etab, x, h0buf, h1buf, xpf, out, myc, As);
}

// --------------------------- launch -----------------------------------------
extern "C" void kernel_launch(void* const* d_in, const int* in_sizes, int n_in,
                              void* d_out, int out_size, void* d_ws, size_t ws_size,
                              hipStream_t stream) {
    const void* emb    = d_in[0];
    const void* wi0    = d_in[1];
    const void* bi0    = d_in[2];
    const void* wh0    = d_in[3];
    const void* wi1    = d_in[4];
    const void* bi1    = d_in[5];
    const void* wh1    = d_in[6];
    const void* ln_g   = d_in[7];
    const void* ln_b   = d_in[8];
    const void* proj_w = d_in[9];
    const void* proj_b = d_in[10];
    const int*  x      = (const int*)d_in[11];
    char* ws = (char*)d_ws;

    // ws map (bytes), total 3,151,936
    float*    etab  = (float*)(ws + 0);             // 1,048,576
    float*    c12   = (float*)(ws + 1048576);       // 2,048
    unsigned* flag  = (unsigned*)(ws + 1050624);    // 64
    f16*      h0buf = (f16*)(ws + 1050688);         // 524,288 ping-pong
    f16*      h1buf = (f16*)(ws + 1574976);         // 524,288 ping-pong
    float*    xpf   = (float*)(ws + 2099264);       // 1,048,576 ping-pong
    unsigned* cnt   = (unsigned*)(ws + 3147840);    // 4,096 (barrier slots + xcd slots)
    if (ws_size < 3151936u) return;  // bail signature: out stays 0

    // zero flag + h/xp ping-pongs + counters/slots: [1050624, 3151936)
    hipMemsetAsync(ws + 1050624, 0, 3151936 - 1050624, stream);

    det_kernel<<<1, 256, 0, stream>>>((const unsigned short*)emb, flag);
    etab_kernel<<<1024, 256, 0, stream>>>(emb, wi0, bi0, flag, etab);
    c12_kernel<<<1, 256, 0, stream>>>(proj_w, ln_g, ln_b, proj_b, flag, c12);
    mega_kernel<<<208, 512, 0, stream>>>(wh0, wi1, wh1, proj_w, ln_g, bi1,
                                         etab, c12, x, flag,
                                         h0buf, h1buf, xpf, d_out, cnt);
}

// Round 7
// 3161.218 us; speedup vs baseline: 3.0428x; 1.0630x over previous
//
#include <hip/hip_runtime.h>
#include <hip/hip_bf16.h>

// ---------------------------------------------------------------------------
// 2-layer tanh RNN (B=128, T=512, H=1024) + LN + vocab projection.
// Persistent fused pipeline, weight-stationary f16 fragments in VGPRs,
// per-group (16 batch rows) DATAFLOW sync (R13).
//
//   L0 : h0[t]   = tanh(etab[x[:,t]] + Wh0·h0[t-1])        t in [0,512)
//   XP : xp[t-1] = wi1·h0[t-1] + bi1                        t in [1,512]
//   L1 : h1[t-2] = tanh(xp[t-2] + Wh1·h1[t-3])             t in [2,513]
//   PR : out[t-3] = algebraic-LN(h1[t-3]) @ (g*pw)^T + c    t in [3,514]
//
// R12->R13: DATAFLOW BARRIER. R12's L2-local global barrier gained only
// ~2% -> the residual ~2.5us/step is jitter amplification: a 26-block
// global barrier takes max-over-26 EVERY step. True deps are narrower
// (verified against ping-pong parities, RAW+WAR):
//   L0@t  waits {L0 sibs, XP} >= t     (reads h0[t-1]; overwrites parity
//                                        read by L0sibs@t-1 and XP@t-1)
//   XP@u  waits {L0, L1} >= u          (reads h0[u-1]; overwrites xpf
//                                        parity read by L1@u-1)
//   L1@v  waits {XP, L1 sibs, PR} >= v (reads xp[v-2], h1[v-3]; overwrites
//                                        parity read by L1sibs/PR @v-1)
//   PR@w  waits {L1} >= w              (reads h1[w-3]; writes only `out`)
// Each role drifts +-1 step vs neighbors -> jitter absorbed, not summed.
// Mechanism per slot unchanged from R12 (PROVEN visible by fast-exit
// timing): sc0 arrival store -> dirty line in the group's XCD L2;
// agent-scope parallel polls served by that L2. Dropped: insurance
// publish-atomic + fallback (was ~0.3us/step ack on wave0's critical
// path), own-slot in the wait set (no store-drain before polling).
// Role-2 ev-load vmcnt folded into the stage vmcnt (one fewer L2 trip).
// SLOW path (non-uniform XCD): R6 global agent-scope barrier, untouched.
//
// R8-proven and unchanged: XCD-local sc0 DATA path (A-tile stage, xp loads,
// h/xp stores -> FETCH 329->67 MB, WRITE 603->81 MB), XCC_ID-uniformity
// detection (FAST only if all 26 blocks of the group share one XCD).
// R11 lesson kept: NEVER spin on sc0-only loads (stale-L1 blindness).
//
// LDS note: As row stride 516 dwords gives the uniform-minimum 8 dwords/bank
// for all wave64 b128 patterns; SQ_LDS_BANK_CONFLICT ~1.09e8 is intrinsic.
//
// INPUT DTYPE DETECTED AT RUNTIME (bf16 vs fp32), flag steers all I/O.
// ws need: 3.01 MB.
// ---------------------------------------------------------------------------

typedef __bf16 bf16;
typedef _Float16 f16;
typedef _Float16 f16x8 __attribute__((ext_vector_type(8)));
typedef float f32x4 __attribute__((ext_vector_type(4)));
typedef unsigned long long u64;

#define TSTEPS 512
#define BATCH  128
#define HID    1024
#define NST    515

__device__ __forceinline__ f32x4 mfma16(f16x8 a, f16x8 b, f32x4 c) {
    return __builtin_amdgcn_mfma_f32_16x16x32_f16(a, b, c, 0, 0, 0);
}

// ---- agent-coherent (sc0|sc1, L1/L2-bypassing) helpers (SLOW path) ----
__device__ __forceinline__ f16x8 lda16(const f16* p) {   // 16B via 2x8B
    union { u64 u[2]; f16x8 v; } c;
    c.u[0] = __hip_atomic_load((const u64*)p,     __ATOMIC_RELAXED, __HIP_MEMORY_SCOPE_AGENT);
    c.u[1] = __hip_atomic_load((const u64*)p + 1, __ATOMIC_RELAXED, __HIP_MEMORY_SCOPE_AGENT);
    return c.v;
}
__device__ __forceinline__ void sth2(f16* p, f16 v) {    // 2B coherent store
    union { f16 f; unsigned short s; } c; c.f = v;
    __hip_atomic_store((unsigned short*)p, c.s, __ATOMIC_RELAXED, __HIP_MEMORY_SCOPE_AGENT);
}
__device__ __forceinline__ void stf4(float* p, float v) { // 4B coherent store
    union { float f; unsigned u; } c; c.f = v;
    __hip_atomic_store((unsigned*)p, c.u, __ATOMIC_RELAXED, __HIP_MEMORY_SCOPE_AGENT);
}
__device__ __forceinline__ float ldf4c(const float* p) {  // 4B coherent load
    union { float f; unsigned u; } c;
    c.u = __hip_atomic_load((const unsigned*)p, __ATOMIC_RELAXED, __HIP_MEMORY_SCOPE_AGENT);
    return c.f;
}

__device__ __forceinline__ unsigned f16bits32(f16 v) {
    union { f16 f; unsigned short s; } c; c.f = v; return (unsigned)c.s;
}

// dual-dtype scalar load (read-only inputs, plain cached)
__device__ __forceinline__ float ldf(const void* p, size_t i, bool f32) {
    return f32 ? ((const float*)p)[i] : (float)((const bf16*)p)[i];
}

// --------------------------- dtype detector --------------------------------
__global__ void det_kernel(const unsigned short* __restrict__ e, unsigned* __restrict__ flag) {
    int tid = threadIdx.x;                       // 1 block x 256
    int cnt = 0;
    for (int i = tid; i < 1024; i += 256) {
        unsigned short u = e[i];
        int ex = (u >> 7) & 0xFF;
        if ((ex >= 110 && ex <= 131) || u == 0) cnt++;
    }
    __shared__ int sh[256];
    sh[tid] = cnt; __syncthreads();
    for (int s = 128; s > 0; s >>= 1) { if (tid < s) sh[tid] += sh[tid + s]; __syncthreads(); }
    if (tid == 0) *flag = (sh[0] >= 768) ? 0u : 1u;
}

// --------------------------- setup kernels ---------------------------------
__global__ void etab_kernel(const void* __restrict__ emb, const void* __restrict__ wi0,
                            const void* __restrict__ bi0, const unsigned* __restrict__ flag,
                            float* __restrict__ etab) {
    const bool f32 = (*flag != 0);
    int i = blockIdx.x * 256 + threadIdx.x;      // 1024 blocks
    int v = i >> 10, ch = i & 1023;
    float s = ldf(bi0, ch, f32);
    for (int e = 0; e < 512; ++e)
        s += ldf(emb, (size_t)v * 512 + e, f32) * ldf(wi0, (size_t)ch * 512 + e, f32);
    etab[i] = s;
}

__global__ void c12_kernel(const void* __restrict__ pw, const void* __restrict__ g,
                           const void* __restrict__ be, const void* __restrict__ pb,
                           const unsigned* __restrict__ flag, float* __restrict__ c12) {
    const bool f32 = (*flag != 0);
    int v = threadIdx.x;                         // 1 block x 256
    float a = 0.f, b = 0.f;
    for (int k = 0; k < 1024; ++k) {
        float w = ldf(pw, (size_t)v * 1024 + k, f32);
        a += (float)(f16)(w * ldf(g, k, f32));
        b += w * ldf(be, k, f32);
    }
    c12[v] = a;
    c12[256 + v] = b + ldf(pb, v, f32);
}

// --------------------------- templated step loop ---------------------------
// FAST=true : group-private DATA via sc0 (XCD-local L2); DATAFLOW sync via
//             sc0 arrival slots + role-subset agent-scope polling.
// FAST=false: R6 agent-scope (sc0|sc1, IF) path + global barrier.
template<bool FAST>
__device__ __forceinline__ void run_loop(
    const int role, const int rid, const int gbase,
    const int tid, const int lane, const int n, const int quad,
    const int ch, const int outv,
    const f16x8 (&wf)[32], const float bias, const float c1v, const float c2v,
    const bool f32io,
    const float* __restrict__ etab, const int* __restrict__ x,
    f16* __restrict__ h0buf, f16* __restrict__ h1buf, float* __restrict__ xpf,
    void* __restrict__ out, unsigned* __restrict__ myc,
    f16 (&As)[16][1032])
{
    // dataflow need-mask: which slot (0..25) must reach t+1 before I may
    // proceed to step t+1. Own slot excluded (no store-drain needed).
    bool need = false;
    if (role == 0)      need = (lane < 16) && (lane != rid);            // L0,XP
    else if (role == 1) need = (lane < 8) || (lane >= 16 && lane < 24); // L0,L1
    else if (role == 2) need = (lane >= 8 && lane < 26) && (lane != rid); // XP,L1,PR
    else                need = (lane >= 16 && lane < 24);               // L1

    for (int t = 0; t < NST; ++t) {
        bool active;
        f16* rbuf;
        if (role == 0)      { active = (t < 512);            rbuf = h0buf; }
        else if (role == 1) { active = (t >= 1 && t <= 512); rbuf = h0buf; }
        else if (role == 2) { active = (t >= 2 && t <= 513); rbuf = h1buf; }
        else                { active = (t >= 3 && t <= 514); rbuf = h1buf; }

        if (active) {   // block-uniform
            const f16* Abase = rbuf + ((t + 1) & 1) * (BATCH * HID)
                             + (size_t)gbase * HID;

            // epilogue operands (issued before staging so latency overlaps)
            float ev[4] = {0.f, 0.f, 0.f, 0.f};
            if (role == 0) {
#pragma unroll
                for (int r = 0; r < 4; ++r) {
                    int b = gbase + quad * 4 + r;
                    ev[r] = etab[(size_t)x[b * TSTEPS + t] * HID + ch];
                }
            } else if (role == 2) {
                const float* xs = xpf + (t & 1) * (BATCH * HID);
                if constexpr (FAST) {
                    const float* p0 = xs + (size_t)(gbase + quad * 4 + 0) * HID + ch;
                    const float* p1 = xs + (size_t)(gbase + quad * 4 + 1) * HID + ch;
                    const float* p2 = xs + (size_t)(gbase + quad * 4 + 2) * HID + ch;
                    const float* p3 = xs + (size_t)(gbase + quad * 4 + 3) * HID + ch;
                    // no vmcnt here: the stage asm's vmcnt(0) drains these;
                    // ev is consumed only after that point.
                    asm volatile(
                        "global_load_dword %0, %4, off sc0\n\t"
                        "global_load_dword %1, %5, off sc0\n\t"
                        "global_load_dword %2, %6, off sc0\n\t"
                        "global_load_dword %3, %7, off sc0"
                        : "=&v"(ev[0]), "=&v"(ev[1]), "=&v"(ev[2]), "=&v"(ev[3])
                        : "v"(p0), "v"(p1), "v"(p2), "v"(p3)
                        : "memory");
                } else {
#pragma unroll
                    for (int r = 0; r < 4; ++r)
                        ev[r] = ldf4c(xs + (size_t)(gbase + quad * 4 + r) * HID + ch);
                }
            }

            // ---- cooperative A-tile stage: 32 KB, once per block ----
            if constexpr (FAST) {
                const f16* ga[4]; f16* da[4];
#pragma unroll
                for (int it = 0; it < 4; ++it) {
                    int idx = it * 512 + tid;        // 2048 chunks of 16B
                    int row = idx >> 7, col = (idx & 127) << 3;
                    ga[it] = Abase + (size_t)row * HID + col;
                    da[it] = &As[row][col];
                }
                f32x4 v0, v1, v2, v3;
                asm volatile(
                    "global_load_dwordx4 %0, %4, off sc0\n\t"
                    "global_load_dwordx4 %1, %5, off sc0\n\t"
                    "global_load_dwordx4 %2, %6, off sc0\n\t"
                    "global_load_dwordx4 %3, %7, off sc0\n\t"
                    "s_waitcnt vmcnt(0)"
                    : "=&v"(v0), "=&v"(v1), "=&v"(v2), "=&v"(v3)
                    : "v"(ga[0]), "v"(ga[1]), "v"(ga[2]), "v"(ga[3])
                    : "memory");
                *(f32x4*)da[0] = v0;
                *(f32x4*)da[1] = v1;
                *(f32x4*)da[2] = v2;
                *(f32x4*)da[3] = v3;
            } else {
#pragma unroll
                for (int it = 0; it < 4; ++it) {
                    int idx = it * 512 + tid;
                    int row = idx >> 7, col = (idx & 127) << 3;
                    f16x8 v = lda16(Abase + (size_t)row * HID + col);
                    *(f16x8*)&As[row][col] = v;
                }
            }

            __syncthreads();    // A-tile visible to all waves

            float mu = 0.f, rs = 0.f;
            if (role == 3) {    // LN stats from the LDS copy
                const f16* srow = &As[n][quad * 256];
                float sum = 0.f, sq = 0.f;
#pragma unroll
                for (int i = 0; i < 256; i += 8) {
                    f16x8 hv = *(const f16x8*)(srow + i);
#pragma unroll
                    for (int j = 0; j < 8; ++j) {
                        float e = (float)hv[j];
                        sum += e; sq += e * e;
                    }
                }
                sum += __shfl_xor(sum, 16); sq += __shfl_xor(sq, 16);
                sum += __shfl_xor(sum, 32); sq += __shfl_xor(sq, 32);
                mu = sum * (1.f / 1024.f);
                float var = sq * (1.f / 1024.f) - mu * mu;
                rs = rsqrtf(fmaxf(var, 0.f) + 1e-5f);
            }

            const f16* arow = &As[n][quad * 8];
            f32x4 a0 = {0,0,0,0}, a1 = {0,0,0,0}, a2 = {0,0,0,0}, a3 = {0,0,0,0};
#pragma unroll
            for (int kt = 0; kt < 32; kt += 4) {
                a0 = mfma16(*(const f16x8*)(arow + (kt + 0) * 32), wf[kt + 0], a0);
                a1 = mfma16(*(const f16x8*)(arow + (kt + 1) * 32), wf[kt + 1], a1);
                a2 = mfma16(*(const f16x8*)(arow + (kt + 2) * 32), wf[kt + 2], a2);
                a3 = mfma16(*(const f16x8*)(arow + (kt + 3) * 32), wf[kt + 3], a3);
            }
            f32x4 acc = (a0 + a1) + (a2 + a3);

            if (role == 0 || role == 2) {
                f16* dw = ((role == 0) ? h0buf : h1buf) + (t & 1) * (BATCH * HID);
                if constexpr (FAST) {
                    unsigned u0 = f16bits32((f16)tanhf(acc[0] + ev[0]));
                    unsigned u1 = f16bits32((f16)tanhf(acc[1] + ev[1]));
                    unsigned u2 = f16bits32((f16)tanhf(acc[2] + ev[2]));
                    unsigned u3 = f16bits32((f16)tanhf(acc[3] + ev[3]));
                    f16* q0 = dw + (size_t)(gbase + quad * 4 + 0) * HID + ch;
                    f16* q1 = dw + (size_t)(gbase + quad * 4 + 1) * HID + ch;
                    f16* q2 = dw + (size_t)(gbase + quad * 4 + 2) * HID + ch;
                    f16* q3 = dw + (size_t)(gbase + quad * 4 + 3) * HID + ch;
                    // in-asm vmcnt(0): stores acked at XCD L2 BEFORE this wave
                    // reaches __syncthreads and the arrival store.
                    asm volatile(
                        "global_store_short %4, %0, off sc0\n\t"
                        "global_store_short %5, %1, off sc0\n\t"
                        "global_store_short %6, %2, off sc0\n\t"
                        "global_store_short %7, %3, off sc0\n\t"
                        "s_waitcnt vmcnt(0)"
                        :: "v"(u0), "v"(u1), "v"(u2), "v"(u3),
                           "v"(q0), "v"(q1), "v"(q2), "v"(q3)
                        : "memory");
                } else {
#pragma unroll
                    for (int r = 0; r < 4; ++r) {
                        int b = gbase + quad * 4 + r;
                        sth2(dw + (size_t)b * HID + ch, (f16)tanhf(acc[r] + ev[r]));
                    }
                }
            } else if (role == 1) {
                float* dw = xpf + ((t + 1) & 1) * (BATCH * HID);
                if constexpr (FAST) {
                    float w0 = acc[0] + bias, w1 = acc[1] + bias;
                    float w2 = acc[2] + bias, w3 = acc[3] + bias;
                    float* q0 = dw + (size_t)(gbase + quad * 4 + 0) * HID + ch;
                    float* q1 = dw + (size_t)(gbase + quad * 4 + 1) * HID + ch;
                    float* q2 = dw + (size_t)(gbase + quad * 4 + 2) * HID + ch;
                    float* q3 = dw + (size_t)(gbase + quad * 4 + 3) * HID + ch;
                    asm volatile(
                        "global_store_dword %4, %0, off sc0\n\t"
                        "global_store_dword %5, %1, off sc0\n\t"
                        "global_store_dword %6, %2, off sc0\n\t"
                        "global_store_dword %7, %3, off sc0\n\t"
                        "s_waitcnt vmcnt(0)"
                        :: "v"(w0), "v"(w1), "v"(w2), "v"(w3),
                           "v"(q0), "v"(q1), "v"(q2), "v"(q3)
                        : "memory");
                } else {
#pragma unroll
                    for (int r = 0; r < 4; ++r) {
                        int b = gbase + quad * 4 + r;
                        stf4(dw + (size_t)b * HID + ch, acc[r] + bias);
                    }
                }
            } else {
                int s = t - 3;
#pragma unroll
                for (int r = 0; r < 4; ++r) {
                    int m = quad * 4 + r;
                    float mm = __shfl(mu, m), rr = __shfl(rs, m);
                    float lv = rr * acc[r] - rr * mm * c1v + c2v;
                    size_t oi = ((size_t)(gbase + m) * TSTEPS + s) * 256 + outv;
                    if (f32io) ((float*)out)[oi] = lv;
                    else       ((bf16*)out)[oi]  = (bf16)lv;
                }
            }
        }

        // ---- per-group sync ----
        __syncthreads();    // all waves' data stores drained (asm vmcnt(0))
        if constexpr (FAST) {
            // DATAFLOW: publish arrival (sc0 -> this XCD's L2, after data),
            // then wait only on the role's need-subset via agent-scope polls
            // (served by the same L2; R11 proved sc0-only polls stale-L1).
            const unsigned want = (unsigned)(t + 1);
            if (tid < 64) {      // wave 0
                if (lane == 0) {
                    unsigned* ms = myc + rid;
                    asm volatile("global_store_dword %0, %1, off sc0"
                                 :: "v"(ms), "v"(want) : "memory");
                }
                for (;;) {
                    unsigned v = want;
                    if (need)
                        v = __hip_atomic_load(myc + lane, __ATOMIC_RELAXED,
                                              __HIP_MEMORY_SCOPE_AGENT);
                    if (__all(v >= want)) break;
                    __builtin_amdgcn_s_sleep(1);
                }
            }
        } else {
            if (tid == 0) {
                __hip_atomic_fetch_add(myc, 1u, __ATOMIC_RELAXED, __HIP_MEMORY_SCOPE_AGENT);
                const unsigned tgt = 26u * (unsigned)(t + 1);
                while (__hip_atomic_load(myc, __ATOMIC_RELAXED, __HIP_MEMORY_SCOPE_AGENT) < tgt)
                    __builtin_amdgcn_s_sleep(1);
            }
        }
        __syncthreads();
    }
}

// --------------------------- persistent mega kernel ------------------------
// grid 208 = 8 groups x 26 blocks; 512 thr (8 waves).
// rid = bid>>3: 0-7 L0, 8-15 XP, 16-23 L1, 24-25 PR.
__global__ __launch_bounds__(512, 2) void mega_kernel(
    const void* __restrict__ wh0, const void* __restrict__ wi1,
    const void* __restrict__ wh1, const void* __restrict__ pw,
    const void* __restrict__ lng, const void* __restrict__ bi1,
    const float* __restrict__ etab, const float* __restrict__ c12,
    const int* __restrict__ x, const unsigned* __restrict__ flag,
    f16* __restrict__ h0buf, f16* __restrict__ h1buf, float* __restrict__ xpf,
    void* __restrict__ out, unsigned* __restrict__ cnt)
{
    const bool f32io = (*flag != 0);
    const int bid  = blockIdx.x;
    const int g    = bid & 7, rid = bid >> 3;
    const int role = rid >> 3;                   // 0 L0, 1 XP, 2 L1, 3 PR
    const int slice = rid & 7;
    const int tid  = threadIdx.x;
    const int wave = tid >> 6, lane = tid & 63;
    const int n    = lane & 15, quad = lane >> 4;
    const int gbase = g * 16;
    // FAST: cnt[g*32 + 0..25] per-block arrival slots (dataflow).
    // SLOW: cnt[g*32] group counter. Regions disjoint across groups.
    unsigned* const myc = cnt + g * 32;

    // A-tile staging buffer: 16 rows x 1032 (stride 516 dwords -> uniform
    // 8 dwords/bank for all b128 patterns, the wave64 minimum). 33 KB LDS.
    __shared__ __align__(16) f16 As[16][1032];

    // stationary f16 weight fragments: 32 x f16x8 = 128 VGPR
    f16x8 wf[32];
    float bias = 0.f, c1v = 0.f, c2v = 0.f;
    int ch = 0, outv = 0;
    if (role < 3) {
        ch = slice * 128 + wave * 16 + n;
        const void* W = (role == 0) ? wh0 : ((role == 1) ? wi1 : wh1);
#pragma unroll
        for (int kt = 0; kt < 32; ++kt) {
            f16x8 t;
#pragma unroll
            for (int j = 0; j < 8; ++j)
                t[j] = (f16)ldf(W, (size_t)ch * HID + kt * 32 + quad * 8 + j, f32io);
            wf[kt] = t;
        }
        if (role == 1) bias = ldf(bi1, ch, f32io);
    } else {
        int tile = slice * 8 + wave;             // 0..15
        outv = tile * 16 + n;
#pragma unroll
        for (int kt = 0; kt < 32; ++kt) {
            f16x8 t;
#pragma unroll
            for (int j = 0; j < 8; ++j) {
                int k = kt * 32 + quad * 8 + j;
                t[j] = (f16)(ldf(pw, (size_t)outv * HID + k, f32io) * ldf(lng, k, f32io));
            }
            wf[kt] = t;
        }
        c1v = c12[outv];
        c2v = c12[256 + outv];
    }

    // ---- XCD-uniformity detection (agent-scope; once) ----
    // Slots cnt[256+bid] hold 0x100|xcc after publish; memset zeroed them.
    // Publish-then-wait over co-resident blocks (same premise as the main
    // sync, proven over 515 steps in R6/R8/R12) -> cannot deadlock.
    unsigned xcc = 0;
    asm volatile("s_getreg_b32 %0, hwreg(HW_REG_XCC_ID)" : "=s"(xcc));
    xcc &= 0xFu;
    __shared__ int fsh;
    if (tid == 0) {
        const unsigned my = 0x100u | xcc;
        __hip_atomic_store(cnt + 256 + bid, my, __ATOMIC_RELAXED, __HIP_MEMORY_SCOPE_AGENT);
        int ok = 1;
        for (int r = 0; r < 26; ++r) {
            unsigned v;
            for (;;) {
                v = __hip_atomic_load(cnt + 256 + g + 8 * r, __ATOMIC_RELAXED, __HIP_MEMORY_SCOPE_AGENT);
                if (v & 0x100u) break;
                __builtin_amdgcn_s_sleep(2);
            }
            if (v != my) ok = 0;
        }
        fsh = ok;
    }
    __syncthreads();
    const bool fast = (fsh != 0);

    if (fast)
        run_loop<true >(role, rid, gbase, tid, lane, n, quad, ch, outv, wf, bias, c1v, c2v,
                        f32io, etab, x, h0buf, h1buf, xpf, out, myc, As);
    else
        run_loop<false>(role, rid, gbase, tid, lane, n, quad, ch, outv, wf, bias, c1v, c2v,
                        f32io, etab, x, h0buf, h1buf, xpf, out, myc, As);
}

// --------------------------- launch -----------------------------------------
extern "C" void kernel_launch(void* const* d_in, const int* in_sizes, int n_in,
                              void* d_out, int out_size, void* d_ws, size_t ws_size,
                              hipStream_t stream) {
    const void* emb    = d_in[0];
    const void* wi0    = d_in[1];
    const void* bi0    = d_in[2];
    const void* wh0    = d_in[3];
    const void* wi1    = d_in[4];
    const void* bi1    = d_in[5];
    const void* wh1    = d_in[6];
    const void* ln_g   = d_in[7];
    const void* ln_b   = d_in[8];
    const void* proj_w = d_in[9];
    const void* proj_b = d_in[10];
    const int*  x      = (const int*)d_in[11];
    char* ws = (char*)d_ws;

    // ws map (bytes), total 3,151,936
    float*    etab  = (float*)(ws + 0);             // 1,048,576
    float*    c12   = (float*)(ws + 1048576);       // 2,048
    unsigned* flag  = (unsigned*)(ws + 1050624);    // 64
    f16*      h0buf = (f16*)(ws + 1050688);         // 524,288 ping-pong
    f16*      h1buf = (f16*)(ws + 1574976);         // 524,288 ping-pong
    float*    xpf   = (float*)(ws + 2099264);       // 1,048,576 ping-pong
    unsigned* cnt   = (unsigned*)(ws + 3147840);    // 4,096 (arrival + xcd slots)
    if (ws_size < 3151936u) return;  // bail signature: out stays 0

    // zero flag + h/xp ping-pongs + counters/slots: [1050624, 3151936)
    hipMemsetAsync(ws + 1050624, 0, 3151936 - 1050624, stream);

    det_kernel<<<1, 256, 0, stream>>>((const unsigned short*)emb, flag);
    etab_kernel<<<1024, 256, 0, stream>>>(emb, wi0, bi0, flag, etab);
    c12_kernel<<<1, 256, 0, stream>>>(proj_w, ln_g, ln_b, proj_b, flag, c12);
    mega_kernel<<<208, 512, 0, stream>>>(wh0, wi1, wh1, proj_w, ln_g, bi1,
                                         etab, c12, x, flag,
                                         h0buf, h1buf, xpf, d_out, cnt);
}